// Round 4
// baseline (1490.811 us; speedup 1.0000x reference)
//
#include <hip/hip_runtime.h>

typedef _Float16 f16;
typedef _Float16 f16x2 __attribute__((ext_vector_type(2)));
typedef _Float16 f16x8 __attribute__((ext_vector_type(8)));
typedef float f32x4 __attribute__((ext_vector_type(4)));

#define MFMA(a,b,c) __builtin_amdgcn_mfma_f32_16x16x32_f16(a,b,c,0,0,0)

constexpr int B_ = 2048, V_ = 128, EGO_ = 15, H_ = 256;
constexpr int MT = 16;           // batch rows per group
constexpr int ENC_KT = 9;        // enc K = 288; kt 0-3 own, 4-7 partner, 8 x
constexpr int HSTR = 168;        // enc LDS row stride
constexpr int DSTRD = 264;       // dec hbuf row stride (16B-aligned, bank-spread)

// JOURNAL: R9 phase-split+per-wave flags (1316); R10 sc1 scope fix: zero delta
// -> agent-scope ops are L2-bypassing + LLC-uncached, every exchange hop is an
// HBM-class RT. R11 sc0 same-XCD fast path: HUNG -- stale per-XCD L2 lines
// across graph replays can never be invalidated (no cross-XCD coherence), so
// replay>=2 reads last run's flags/magic. Lesson: NO sc0 cross-block state,
// ever. R12 (this): decoder rebuilt as M-SPLIT -- 128 blocks x 16 rows, FULL
// Whh2 (512KB) resident per CU (96 frags/wave RF + 32 frags/wave LDS), xd as
// packed f16x2 regs, double-buffered hbuf, pi head fully local. Zero global
// traffic in the recurrent loop, one barrier/step. Encoder reverted to the
// R2-proven pair-split sc1 form verbatim.

__device__ __forceinline__ float sigf(float x){ return 1.f/(1.f+__expf(-x)); }
__device__ __forceinline__ float tanh_fast(float x){ return 1.f - 2.f/(1.f+__expf(2.f*x)); }

// relaxed agent-scope ops (enc exchange): L2-bypass, memory-class RT, proven.
__device__ __forceinline__ void st_u32(uint32_t* p, uint32_t v){
    __hip_atomic_store(p, v, __ATOMIC_RELAXED, __HIP_MEMORY_SCOPE_AGENT);
}
__device__ __forceinline__ uint32_t ld_u32(const uint32_t* p){
    return __hip_atomic_load(p, __ATOMIC_RELAXED, __HIP_MEMORY_SCOPE_AGENT);
}
__device__ __forceinline__ void bypass_ld4(f16x8& d0, f16x8& d1, f16x8& d2, f16x8& d3,
                                           const f16* p0, const f16* p1,
                                           const f16* p2, const f16* p3){
    asm volatile(
        "global_load_dwordx4 %0, %4, off sc1\n\t"
        "global_load_dwordx4 %1, %5, off sc1\n\t"
        "global_load_dwordx4 %2, %6, off sc1\n\t"
        "global_load_dwordx4 %3, %7, off sc1\n\t"
        "s_waitcnt vmcnt(0)"
        : "=&v"(d0), "=&v"(d1), "=&v"(d2), "=&v"(d3)
        : "v"(p0), "v"(p1), "v"(p2), "v"(p3)
        : "memory");
}
__device__ __forceinline__ void bypass_st(f16* p, f16x8 v){
    asm volatile("global_store_dwordx4 %0, %1, off sc1" :: "v"(p), "v"(v) : "memory");
}
__device__ __forceinline__ void vm_drain(){
    asm volatile("s_waitcnt vmcnt(0)" ::: "memory");
}

// ---- prepack enc (R2 layout): kt 0..3 own half, 4..7 partner half, 8 = x ----
__global__ void prepack_enc(const float* __restrict__ Whh1, const float* __restrict__ Wih1,
                            f16* __restrict__ dst){
    int id = blockIdx.x*256 + threadIdx.x;
    if (id >= 2*4*8*ENC_KT*64) return;
    int L = id & 63; int c = id >> 6;
    int kt = c % ENC_KT; c /= ENC_KT;
    int nt = c & 7; c >>= 3;
    int w = c & 3; int hb = c >> 2;
    int n = (nt>>1)*256 + hb*128 + w*32 + (nt&1)*16 + (L&15);
    int kb = (L>>4)*8;
    #pragma unroll
    for (int j=0;j<8;++j){
        int kin = kb + j;
        int k;
        if (kt < 4)      k = hb*128 + kt*32 + kin;
        else if (kt < 8) k = (1-hb)*128 + (kt-4)*32 + kin;
        else             k = 256 + kin;
        float x = (k < 256) ? Whh1[n*256 + k] : ((k < 271) ? Wih1[n*15 + (k-256)] : 0.f);
        dst[(size_t)id*8 + j] = (f16)x;
    }
}
// ---- prepack dec (NEW M-split layout): fid = ((w*4+cg)*4+gate)*8+kt ---------
__global__ void prepack_dec(const float* __restrict__ Whh2, f16* __restrict__ dst){
    int id = blockIdx.x*256 + threadIdx.x;   // id = fid*64 + L, fid < 512
    if (id >= 512*64) return;
    int L = id & 63; int fid = id >> 6;
    int kt = fid & 7; int c = fid >> 3;
    int gate = c & 3; c >>= 2;
    int cg = c & 3; int w = c >> 2;
    int n = gate*256 + w*64 + cg*16 + (L&15);
    int kb = kt*32 + (L>>4)*8;
    #pragma unroll
    for (int j=0;j<8;++j) dst[(size_t)id*8 + j] = (f16)Whh2[n*256 + kb + j];
}
__global__ void bias_kernel(const float* bih1,const float* bhh1,const float* bih2,
                            const float* bhh2,float* be,float* bd){
    int i = blockIdx.x*256 + threadIdx.x;
    if (i < 1024){ be[i]=bih1[i]+bhh1[i]; bd[i]=bih2[i]+bhh2[i]; }
}
__global__ void convert_kernel(const float* __restrict__ src, f16* __restrict__ dst, int n){
    int i = blockIdx.x*256 + threadIdx.x;
    if (i < n) dst[i] = (f16)src[i];
}

// ---- encoder: R2-proven pair-split (i <-> i^128), sc1 exchange --------------
__global__ __launch_bounds__(256,1) void encoder_kernel(
    const float* __restrict__ state, const int* __restrict__ lengths,
    const f16* __restrict__ Wp, const float* __restrict__ bias,
    f16* __restrict__ henc, f16* __restrict__ ebuf, int* __restrict__ flags)
{
    __shared__ __align__(16) f16 wlds[4*8*4*64*8];   // 128 KB: partner-half kts
    __shared__ __align__(16) f16 hcat[MT*HSTR];
    __shared__ int lmax_s;
    const int tid = threadIdx.x;
    const int wave = tid>>6, lane = tid&63, lr = lane&15, quad = lane>>4;
    const int bid = blockIdx.x, hb = bid>>7, g = bid&127, pbid = bid^128;
    const int row0 = g*MT;
    const int xr = tid>>4, xc = tid&15;

    for (int i=tid;i<MT*HSTR;i+=256) hcat[i] = (f16)0.f;
    if (tid < 64){
        int l = (lane<16) ? lengths[row0+lane] : 0;
        #pragma unroll
        for (int m=1;m<16;m<<=1){ int o = __shfl_xor(l, m, 64); l = (o>l)?o:l; }
        if (lane==0) lmax_s = l;
    }

    int len_r[4];
    #pragma unroll
    for (int r=0;r<4;++r) len_r[r] = lengths[row0 + quad*4 + r];

    float bias_v[8];
    #pragma unroll
    for (int nt=0;nt<8;++nt)
        bias_v[nt] = bias[(nt>>1)*256 + hb*128 + wave*32 + (nt&1)*16 + lr];

    const f16x8* Wb = (const f16x8*)Wp + (size_t)((hb*4+wave)*8*ENC_KT)*64;
    f16x8 wreg[8][5];
    #pragma unroll
    for (int nt=0;nt<8;++nt){
        #pragma unroll
        for (int kt=0;kt<4;++kt) wreg[nt][kt] = Wb[(nt*ENC_KT + kt)*64 + lane];
        wreg[nt][4] = Wb[(nt*ENC_KT + 8)*64 + lane];
    }
    f16x8* wl = (f16x8*)wlds + (size_t)wave*(8*4*64);
    #pragma unroll
    for (int nt=0;nt<8;++nt)
        #pragma unroll
        for (int p=0;p<4;++p)
            wl[(nt*4 + p)*64 + lane] = Wb[(nt*ENC_KT + 4 + p)*64 + lane];

    __syncthreads();
    const int rr = tid/15, cc = tid - rr*15;
    const size_t xbase = (size_t)(row0+rr)*V_*EGO_ + cc;
    float xreg = 0.f;
    if (tid < 240){
        hcat[rr*HSTR + 128 + cc] = (f16)state[xbase];
        xreg = state[xbase + EGO_];
    }
    float c_reg[8], h_reg[8];
    #pragma unroll
    for (int i=0;i<8;++i){ c_reg[i]=0.f; h_reg[i]=0.f; }
    __syncthreads();
    const int Lmax = lmax_s;

    for (int t=0;t<Lmax;++t){
        uint32_t f0 = (uint32_t)t;
        if (t > 0 && lane < 4) f0 = ld_u32((const uint32_t*)&flags[pbid*4 + lane]);
        f32x4 acc[8];
        #pragma unroll
        for (int nt=0;nt<8;++nt) acc[nt] = (f32x4){bias_v[nt],bias_v[nt],bias_v[nt],bias_v[nt]};
        #pragma unroll
        for (int kt=0;kt<4;++kt){
            f16x8 a = *(const f16x8*)&hcat[lr*HSTR + kt*32 + quad*8];
            #pragma unroll
            for (int nt=0;nt<8;++nt) acc[nt] = MFMA(a, wreg[nt][kt], acc[nt]);
        }
        {
            f16x8 a = *(const f16x8*)&hcat[lr*HSTR + 128 + quad*8];
            #pragma unroll
            for (int nt=0;nt<8;++nt) acc[nt] = MFMA(a, wreg[nt][4], acc[nt]);
        }
        if (t > 0){
            f16x8 b0[8];
            #pragma unroll
            for (int nt=0;nt<8;++nt) b0[nt] = wl[(nt*4 + 0)*64 + lane];
            if (lane < 4){
                while (f0 < (uint32_t)t){
                    __builtin_amdgcn_s_sleep(1);
                    f0 = ld_u32((const uint32_t*)&flags[pbid*4 + lane]);
                }
            }
            const f16* src = ebuf + ((size_t)((t-1)&1)*256 + pbid)*2048 + lr*128 + quad*8;
            f16x8 a0,a1,a2,a3;
            bypass_ld4(a0,a1,a2,a3, src, src+32, src+64, src+96);
            #pragma unroll
            for (int nt=0;nt<8;++nt) acc[nt] = MFMA(a0, b0[nt], acc[nt]);
            #pragma unroll
            for (int nt=0;nt<8;++nt) acc[nt] = MFMA(a1, wl[(nt*4+1)*64+lane], acc[nt]);
            #pragma unroll
            for (int nt=0;nt<8;++nt) acc[nt] = MFMA(a2, wl[(nt*4+2)*64+lane], acc[nt]);
            #pragma unroll
            for (int nt=0;nt<8;++nt) acc[nt] = MFMA(a3, wl[(nt*4+3)*64+lane], acc[nt]);
        }
        __syncthreads();                     // B2
        #pragma unroll
        for (int s=0;s<2;++s){
            #pragma unroll
            for (int r=0;r<4;++r){
                int idx = s*4 + r;
                float gi = acc[s][r],   gf = acc[2+s][r];
                float gg = acc[4+s][r], go = acc[6+s][r];
                float cn = sigf(gf)*c_reg[idx] + sigf(gi)*tanh_fast(gg);
                float hn = sigf(go)*tanh_fast(cn);
                bool upd = (t < len_r[r]);
                c_reg[idx] = upd ? cn : c_reg[idx];
                h_reg[idx] = upd ? hn : h_reg[idx];
                hcat[(quad*4+r)*HSTR + wave*32 + s*16 + lr] = (f16)h_reg[idx];
            }
        }
        if (tid < 240) hcat[rr*HSTR + 128 + cc] = (f16)xreg;
        __syncthreads();                     // B3
        {
            f16x8 h8 = *(const f16x8*)&hcat[xr*HSTR + xc*8];
            f16* dst = ebuf + ((size_t)(t&1)*256 + bid)*2048 + xr*128 + xc*8;
            bypass_st(dst, h8);
        }
        vm_drain();
        if (lane == 0) st_u32((uint32_t*)&flags[bid*4 + wave], (uint32_t)(t+1));
        if (tid < 240){
            int tn = (t+2 < V_) ? (t+2) : (V_-1);
            xreg = state[xbase + (size_t)tn*EGO_];
        }
    }
    #pragma unroll
    for (int s=0;s<2;++s)
        #pragma unroll
        for (int r=0;r<4;++r)
            henc[(size_t)(row0+quad*4+r)*H_ + hb*128 + wave*32 + s*16 + lr] = (f16)h_reg[s*4+r];
}

// ---- generic GEMM: C = act(A[M,K] @ W[N,K]^T + bias) ----
template<bool RELU, bool F32OUT>
__global__ __launch_bounds__(256,2) void gemm_kernel(
    const f16* __restrict__ A, const f16* __restrict__ W,
    const float* __restrict__ bias, void* __restrict__ outp,
    int M, int N, int K)
{
    constexpr int ASTR = 40;
    __shared__ __align__(16) f16 As[64*ASTR];
    __shared__ __align__(16) f16 Ws[64*ASTR];
    const int tid = threadIdx.x;
    const int wave = tid>>6, lane = tid&63, lr = lane&15, quad = lane>>4;
    const int n0 = blockIdx.x*64, m0 = blockIdx.y*64;
    const int lrow = tid>>2, lk8 = (tid&3)*8;

    f32x4 acc[4];
    #pragma unroll
    for (int mt=0;mt<4;++mt) acc[mt] = (f32x4){0.f,0.f,0.f,0.f};

    for (int k0=0;k0<K;k0+=32){
        __syncthreads();
        *(f16x8*)&As[lrow*ASTR + lk8] = *(const f16x8*)&A[(size_t)(m0+lrow)*K + k0 + lk8];
        *(f16x8*)&Ws[lrow*ASTR + lk8] = *(const f16x8*)&W[(size_t)(n0+lrow)*K + k0 + lk8];
        __syncthreads();
        f16x8 b = *(const f16x8*)&Ws[(wave*16+lr)*ASTR + quad*8];
        #pragma unroll
        for (int mt=0;mt<4;++mt){
            f16x8 a = *(const f16x8*)&As[(mt*16+lr)*ASTR + quad*8];
            acc[mt] = MFMA(a, b, acc[mt]);
        }
    }
    float bv = bias[n0 + wave*16 + lr];
    #pragma unroll
    for (int mt=0;mt<4;++mt){
        #pragma unroll
        for (int r=0;r<4;++r){
            float v = acc[mt][r] + bv;
            if (RELU) v = fmaxf(v, 0.f);
            int m = m0 + mt*16 + quad*4 + r, n = n0 + wave*16 + lr;
            if (F32OUT) ((float*)outp)[(size_t)m*N + n] = v;
            else        ((f16*)outp)[(size_t)m*N + n] = (f16)v;
        }
    }
}

// ---- decoder: M-SPLIT. 128 blocks x 16 rows, full Whh2 resident per CU. ----
// Per wave: cols wave*64 + cg*16 + lr (cg=0..3); gates i,f,g,o = ntile gate idx.
// Weights: kt 0..5 in RF (96 frags = 384 VGPR), kt 6..7 in LDS (128 KB).
// xd (= x@Wih2+biasD) packed f16x2 in 32 VGPRs. hbuf double-buffered ->
// ONE barrier per step, zero global traffic in the loop.
__global__ __launch_bounds__(256,1) void decoder_kernel(
    const int* __restrict__ lengths, const f16* __restrict__ Wp,
    const float* __restrict__ xdec, const float* __restrict__ Wpi,
    const float* __restrict__ bpi, float* __restrict__ out)
{
    __shared__ __align__(16) f16 wlds[4*32*64*8];    // 128 KB: kt 6..7
    __shared__ __align__(16) f16 hbuf[2][MT*DSTRD];  // 16.5 KB dbuf
    __shared__ float part[2][4][16][2];
    __shared__ float wpi_s[2][256];
    __shared__ int lmax_s;
    const int tid = threadIdx.x;
    const int wave = tid>>6, lane = tid&63, lr = lane&15, quad = lane>>4;
    const int bid = blockIdx.x;              // 128 blocks
    const int row0 = bid*MT;

    for (int i=tid;i<2*MT*DSTRD;i+=256) ((f16*)hbuf)[i] = (f16)0.f;
    if (tid < 64){
        int l = (lane<16) ? lengths[row0+lane] : 0;
        #pragma unroll
        for (int m=1;m<16;m<<=1){ int o = __shfl_xor(l, m, 64); l = (o>l)?o:l; }
        if (lane==0) lmax_s = l;
    }
    wpi_s[0][tid] = Wpi[tid];
    wpi_s[1][tid] = Wpi[256 + tid];

    // xd: 64 scattered f32 -> 32 packed f16x2 regs (row pairs per quad)
    f16x2 xd_pk[4][4][2];
    #pragma unroll
    for (int cg=0;cg<4;++cg)
        #pragma unroll
        for (int g4=0;g4<4;++g4){
            int n = g4*256 + wave*64 + cg*16 + lr;
            #pragma unroll
            for (int p=0;p<2;++p){
                float v0 = xdec[(size_t)(row0+quad*4+2*p+0)*1024 + n];
                float v1 = xdec[(size_t)(row0+quad*4+2*p+1)*1024 + n];
                xd_pk[cg][g4][p] = (f16x2){(f16)v0,(f16)v1};
            }
        }

    // weights: RF kt 0..5, LDS kt 6..7
    const f16x8* Wb = (const f16x8*)Wp;
    f16x8 wreg[4][4][6];
    #pragma unroll
    for (int cg=0;cg<4;++cg)
        #pragma unroll
        for (int g4=0;g4<4;++g4)
            #pragma unroll
            for (int kt=0;kt<6;++kt)
                wreg[cg][g4][kt] = Wb[(size_t)((((wave*4+cg)*4+g4)*8)+kt)*64 + lane];
    f16x8* wl = (f16x8*)wlds + (size_t)wave*(32*64);
    #pragma unroll
    for (int cg=0;cg<4;++cg)
        #pragma unroll
        for (int g4=0;g4<4;++g4)
            #pragma unroll
            for (int ktt=0;ktt<2;++ktt)
                wl[((cg*4+g4)*2+ktt)*64 + lane] = Wb[(size_t)((((wave*4+cg)*4+g4)*8)+6+ktt)*64 + lane];

    float c_reg[4][4];
    #pragma unroll
    for (int cg=0;cg<4;++cg)
        #pragma unroll
        for (int r=0;r<4;++r) c_reg[cg][r] = 0.f;

    const int m_o = (tid>>1)&15, a_o = tid&1;
    const float bpi_o = bpi[a_o];
    const int len_o = (tid<32) ? lengths[row0+m_o] : 0;
    const size_t outbase = (size_t)(row0+m_o)*V_*2 + a_o;

    __syncthreads();
    const int Lmax = lmax_s;

    for (int t=0;t<Lmax;++t){
        const f16* hb = &hbuf[t&1][0];
        f16* hnb = &hbuf[(t+1)&1][0];
        float spi[4][2];
        #pragma unroll
        for (int r=0;r<4;++r){ spi[r][0]=0.f; spi[r][1]=0.f; }
        #pragma unroll
        for (int cg=0;cg<4;++cg){
            f32x4 acc[4];
            #pragma unroll
            for (int g4=0;g4<4;++g4)
                acc[g4] = (f32x4){ (float)xd_pk[cg][g4][0][0], (float)xd_pk[cg][g4][0][1],
                                   (float)xd_pk[cg][g4][1][0], (float)xd_pk[cg][g4][1][1] };
            #pragma unroll
            for (int kt=0;kt<8;++kt){
                f16x8 a = *(const f16x8*)&hb[lr*DSTRD + kt*32 + quad*8];
                if (kt < 6){
                    #pragma unroll
                    for (int g4=0;g4<4;++g4) acc[g4] = MFMA(a, wreg[cg][g4][kt], acc[g4]);
                } else {
                    #pragma unroll
                    for (int g4=0;g4<4;++g4)
                        acc[g4] = MFMA(a, wl[((cg*4+g4)*2+(kt-6))*64 + lane], acc[g4]);
                }
            }
            const int col = wave*64 + cg*16 + lr;
            const float w0 = wpi_s[0][col], w1 = wpi_s[1][col];
            #pragma unroll
            for (int r=0;r<4;++r){
                float gi = acc[0][r], gf = acc[1][r], gg = acc[2][r], go = acc[3][r];
                float cn = sigf(gf)*c_reg[cg][r] + sigf(gi)*tanh_fast(gg);
                c_reg[cg][r] = cn;
                float hn = sigf(go)*tanh_fast(cn);
                hnb[(quad*4+r)*DSTRD + col] = (f16)hn;
                spi[r][0] += cn*w0;
                spi[r][1] += cn*w1;
            }
        }
        #pragma unroll
        for (int msk=1; msk<16; msk<<=1){
            #pragma unroll
            for (int r=0;r<4;++r){
                spi[r][0] += __shfl_xor(spi[r][0], msk, 64);
                spi[r][1] += __shfl_xor(spi[r][1], msk, 64);
            }
        }
        if (lr == 0){
            #pragma unroll
            for (int r=0;r<4;++r){
                part[t&1][wave][quad*4+r][0] = spi[r][0];
                part[t&1][wave][quad*4+r][1] = spi[r][1];
            }
        }
        __syncthreads();                     // single barrier per step
        if (tid < 32){
            float v = part[t&1][0][m_o][a_o] + part[t&1][1][m_o][a_o]
                    + part[t&1][2][m_o][a_o] + part[t&1][3][m_o][a_o] + bpi_o;
            v = tanh_fast(v);
            out[outbase + (size_t)t*2] = (t < len_o) ? v : 0.f;
        }
    }
    if (tid < 32)
        for (int t=Lmax; t<V_; ++t) out[outbase + (size_t)t*2] = 0.f;
}

extern "C" void kernel_launch(void* const* d_in, const int* in_sizes, int n_in,
                              void* d_out, int out_size, void* d_ws, size_t ws_size,
                              hipStream_t stream) {
    const float* state = (const float*)d_in[0];
    const int*   lengths=(const int*)d_in[1];
    const float* Wih1 = (const float*)d_in[2];
    const float* Whh1 = (const float*)d_in[3];
    const float* bih1 = (const float*)d_in[4];
    const float* bhh1 = (const float*)d_in[5];
    const float* W1   = (const float*)d_in[6];  const float* b1 = (const float*)d_in[7];
    const float* W2   = (const float*)d_in[8];  const float* b2 = (const float*)d_in[9];
    const float* W3   = (const float*)d_in[10]; const float* b3 = (const float*)d_in[11];
    const float* W4   = (const float*)d_in[12]; const float* b4 = (const float*)d_in[13];
    const float* Wih2 = (const float*)d_in[14]; const float* Whh2=(const float*)d_in[15];
    const float* bih2 = (const float*)d_in[16]; const float* bhh2=(const float*)d_in[17];
    const float* Wpi  = (const float*)d_in[18]; const float* bpi =(const float*)d_in[19];
    float* out = (float*)d_out;

    char* p = (char*)d_ws;
    auto alloc = [&](size_t bytes){ char* r = p; p += (bytes + 255) & ~(size_t)255; return r; };
    f16* WencP   = (f16*)alloc((size_t)2*4*8*ENC_KT*64*8*2);
    f16* WdecP   = (f16*)alloc((size_t)512*64*8*2);          // 512KB, M-split layout
    f16* W1f     = (f16*)alloc((size_t)1024*256*2);
    f16* W2f     = (f16*)alloc((size_t)1024*1024*2);
    f16* W3f     = (f16*)alloc((size_t)512*1024*2);
    f16* W4f     = (f16*)alloc((size_t)256*512*2);
    f16* Wih2f   = (f16*)alloc((size_t)1024*256*2);
    float* biasE = (float*)alloc(1024*4);
    float* biasD = (float*)alloc(1024*4);
    f16* henc    = (f16*)alloc((size_t)2048*256*2);
    f16* act1    = (f16*)alloc((size_t)2048*1024*2);
    f16* act2    = (f16*)alloc((size_t)2048*1024*2);
    f16* act3    = (f16*)alloc((size_t)2048*512*2);
    f16* x4      = (f16*)alloc((size_t)2048*256*2);
    float* xdec  = (float*)alloc((size_t)2048*1024*4);
    f16* ebuf    = (f16*)alloc((size_t)2*256*2048*2);
    int* flags   = (int*)alloc((size_t)2048*4);              // enc: 4 ints/block

    hipMemsetAsync(flags, 0, 2048*4, stream);

    prepack_enc<<<(2*4*8*ENC_KT*64+255)/256,256,0,stream>>>(Whh1, Wih1, WencP);
    prepack_dec<<<128,256,0,stream>>>(Whh2, WdecP);
    bias_kernel<<<4,256,0,stream>>>(bih1,bhh1,bih2,bhh2,biasE,biasD);
    convert_kernel<<<(1024*256+255)/256,256,0,stream>>>(W1, W1f, 1024*256);
    convert_kernel<<<(1024*1024+255)/256,256,0,stream>>>(W2, W2f, 1024*1024);
    convert_kernel<<<(512*1024+255)/256,256,0,stream>>>(W3, W3f, 512*1024);
    convert_kernel<<<(256*512+255)/256,256,0,stream>>>(W4, W4f, 256*512);
    convert_kernel<<<(1024*256+255)/256,256,0,stream>>>(Wih2, Wih2f, 1024*256);

    encoder_kernel<<<256,256,0,stream>>>(state, lengths, WencP, biasE, henc, ebuf, flags);

    gemm_kernel<true ,false><<<dim3(16,32),256,0,stream>>>(henc, W1f, b1, act1, 2048,1024,256);
    gemm_kernel<true ,false><<<dim3(16,32),256,0,stream>>>(act1, W2f, b2, act2, 2048,1024,1024);
    gemm_kernel<true ,false><<<dim3( 8,32),256,0,stream>>>(act2, W3f, b3, act3, 2048, 512,1024);
    gemm_kernel<true ,false><<<dim3( 4,32),256,0,stream>>>(act3, W4f, b4, x4,   2048, 256, 512);
    gemm_kernel<false,true ><<<dim3(16,32),256,0,stream>>>(x4, Wih2f, biasD, xdec, 2048,1024,256);

    decoder_kernel<<<128,256,0,stream>>>(lengths, WdecP, xdec, Wpi, bpi, out);
}

// Round 7
// 1326.394 us; speedup vs baseline: 1.1240x; 1.1240x over previous
//
#include <hip/hip_runtime.h>

typedef _Float16 f16;
typedef _Float16 f16x8 __attribute__((ext_vector_type(8)));
typedef float f32x4 __attribute__((ext_vector_type(4)));

#define MFMA(a,b,c) __builtin_amdgcn_mfma_f32_16x16x32_f16(a,b,c,0,0,0)

constexpr int B_ = 2048, V_ = 128, EGO_ = 15, H_ = 256;
constexpr int MT = 16;           // batch rows per group
constexpr int ENC_KT = 9;        // K = 288; kt 0-3 own, 4-7 partner, 8 x
constexpr int DEC_KT = 8;        // K = 256; kt 0-3 own, 4-7 partner
constexpr int HSTR = 168;
constexpr int DSTR = 136;
constexpr int EBSTR = 2112;      // dec ebuf row: 2048 f16 h + 64 f16 (32 f32 pi)

// JOURNAL: R2 = best PASSED (1282us: enc 534 + dec 618), pair-split + sc1
// agent exchange. R10: agent-scope ops are L2-bypassing+LLC-uncached -> each
// exchange hop is an HBM-class RT (~2000cy). R11 sc0 same-XCD path: HUNG
// (stale per-XCD L2 across graph replays) -- never sc0 cross-block state.
// R12 M-split dec (4w): passed, 797us (1 wave/SIMD, no TLP). R13/R14 8-wave
// M-split: BOTH failed absmax ~1e-2; mappings paper-check 3x -> structure
// parked. R15 (this): R2 verbatim + ONE change -- pi partials piggyback
// inside the decoder's ebuf row (stride 2048->2112 f16, partials at dword
// 1024+tid), written before the existing wave-0 drain (flag 0 covers them),
// read in the SAME vmcnt window as the h ld4 (5-load asm). Removes the
// dedicated pbuf RT (~2000cy) from the decoder's critical path.

__device__ __forceinline__ float sigf(float x){ return 1.f/(1.f+__expf(-x)); }
__device__ __forceinline__ float tanh_fast(float x){ return 1.f - 2.f/(1.f+__expf(2.f*x)); }

// relaxed agent-scope ops: L2-bypass, memory-class RT, replay-safe (proven).
// RULE: cross-block data written via bypass stores MUST be read via bypass loads.
__device__ __forceinline__ void st_u32(uint32_t* p, uint32_t v){
    __hip_atomic_store(p, v, __ATOMIC_RELAXED, __HIP_MEMORY_SCOPE_AGENT);
}
__device__ __forceinline__ uint32_t ld_u32(const uint32_t* p){
    return __hip_atomic_load(p, __ATOMIC_RELAXED, __HIP_MEMORY_SCOPE_AGENT);
}
__device__ __forceinline__ void bypass_ld4(f16x8& d0, f16x8& d1, f16x8& d2, f16x8& d3,
                                           const f16* p0, const f16* p1,
                                           const f16* p2, const f16* p3){
    asm volatile(
        "global_load_dwordx4 %0, %4, off sc1\n\t"
        "global_load_dwordx4 %1, %5, off sc1\n\t"
        "global_load_dwordx4 %2, %6, off sc1\n\t"
        "global_load_dwordx4 %3, %7, off sc1\n\t"
        "s_waitcnt vmcnt(0)"
        : "=&v"(d0), "=&v"(d1), "=&v"(d2), "=&v"(d3)
        : "v"(p0), "v"(p1), "v"(p2), "v"(p3)
        : "memory");
}
// 4x16B h-frags + 1x4B pi partial in ONE vmcnt window (wave 0 of decoder).
__device__ __forceinline__ void bypass_ld4p(f16x8& d0, f16x8& d1, f16x8& d2, f16x8& d3,
                                            uint32_t& pv,
                                            const f16* p0, const f16* p1,
                                            const f16* p2, const f16* p3,
                                            const uint32_t* pp){
    asm volatile(
        "global_load_dwordx4 %0, %5, off sc1\n\t"
        "global_load_dwordx4 %1, %6, off sc1\n\t"
        "global_load_dwordx4 %2, %7, off sc1\n\t"
        "global_load_dwordx4 %3, %8, off sc1\n\t"
        "global_load_dword %4, %9, off sc1\n\t"
        "s_waitcnt vmcnt(0)"
        : "=&v"(d0), "=&v"(d1), "=&v"(d2), "=&v"(d3), "=&v"(pv)
        : "v"(p0), "v"(p1), "v"(p2), "v"(p3), "v"(pp)
        : "memory");
}
__device__ __forceinline__ void bypass_st(f16* p, f16x8 v){
    asm volatile("global_store_dwordx4 %0, %1, off sc1" :: "v"(p), "v"(v) : "memory");
}
__device__ __forceinline__ void vm_drain(){
    asm volatile("s_waitcnt vmcnt(0)" ::: "memory");
}

// ---- prepack: weights -> per-(hb,wave) MFMA B-fragment order, K permuted so
// kt 0..3 = own half (hb*128..), kt 4..7 = partner half, kt 8 = x (enc only).
__global__ void prepack_enc(const float* __restrict__ Whh1, const float* __restrict__ Wih1,
                            f16* __restrict__ dst){
    int id = blockIdx.x*256 + threadIdx.x;
    if (id >= 2*4*8*ENC_KT*64) return;
    int L = id & 63; int c = id >> 6;
    int kt = c % ENC_KT; c /= ENC_KT;
    int nt = c & 7; c >>= 3;
    int w = c & 3; int hb = c >> 2;
    int n = (nt>>1)*256 + hb*128 + w*32 + (nt&1)*16 + (L&15);
    int kb = (L>>4)*8;
    #pragma unroll
    for (int j=0;j<8;++j){
        int kin = kb + j;
        int k;
        if (kt < 4)      k = hb*128 + kt*32 + kin;
        else if (kt < 8) k = (1-hb)*128 + (kt-4)*32 + kin;
        else             k = 256 + kin;
        float x = (k < 256) ? Whh1[n*256 + k] : ((k < 271) ? Wih1[n*15 + (k-256)] : 0.f);
        dst[(size_t)id*8 + j] = (f16)x;
    }
}
__global__ void prepack_dec(const float* __restrict__ Whh2, f16* __restrict__ dst){
    int id = blockIdx.x*256 + threadIdx.x;
    if (id >= 2*4*8*DEC_KT*64) return;
    int L = id & 63; int c = id >> 6;
    int kt = c % DEC_KT; c /= DEC_KT;
    int nt = c & 7; c >>= 3;
    int w = c & 3; int hb = c >> 2;
    int n = (nt>>1)*256 + hb*128 + w*32 + (nt&1)*16 + (L&15);
    int kb = (L>>4)*8;
    #pragma unroll
    for (int j=0;j<8;++j){
        int kin = kb + j;
        int k = (kt < 4) ? (hb*128 + kt*32 + kin) : ((1-hb)*128 + (kt-4)*32 + kin);
        dst[(size_t)id*8 + j] = (f16)Whh2[n*256 + k];
    }
}
__global__ void bias_kernel(const float* bih1,const float* bhh1,const float* bih2,
                            const float* bhh2,float* be,float* bd){
    int i = blockIdx.x*256 + threadIdx.x;
    if (i < 1024){ be[i]=bih1[i]+bhh1[i]; bd[i]=bih2[i]+bhh2[i]; }
}
__global__ void convert_kernel(const float* __restrict__ src, f16* __restrict__ dst, int n){
    int i = blockIdx.x*256 + threadIdx.x;
    if (i < n) dst[i] = (f16)src[i];
}

// ---- encoder: R2-proven pair-split (i <-> i^128), sc1 exchange (VERBATIM) ---
__global__ __launch_bounds__(256,1) void encoder_kernel(
    const float* __restrict__ state, const int* __restrict__ lengths,
    const f16* __restrict__ Wp, const float* __restrict__ bias,
    f16* __restrict__ henc, f16* __restrict__ ebuf, int* __restrict__ flags)
{
    __shared__ __align__(16) f16 wlds[4*8*4*64*8];   // 128 KB: partner-half kts
    __shared__ __align__(16) f16 hcat[MT*HSTR];
    __shared__ int lmax_s;
    const int tid = threadIdx.x;
    const int wave = tid>>6, lane = tid&63, lr = lane&15, quad = lane>>4;
    const int bid = blockIdx.x, hb = bid>>7, g = bid&127, pbid = bid^128;
    const int row0 = g*MT;
    const int xr = tid>>4, xc = tid&15;

    for (int i=tid;i<MT*HSTR;i+=256) hcat[i] = (f16)0.f;
    if (tid < 64){
        int l = (lane<16) ? lengths[row0+lane] : 0;
        #pragma unroll
        for (int m=1;m<16;m<<=1){ int o = __shfl_xor(l, m, 64); l = (o>l)?o:l; }
        if (lane==0) lmax_s = l;
    }

    int len_r[4];
    #pragma unroll
    for (int r=0;r<4;++r) len_r[r] = lengths[row0 + quad*4 + r];

    float bias_v[8];
    #pragma unroll
    for (int nt=0;nt<8;++nt)
        bias_v[nt] = bias[(nt>>1)*256 + hb*128 + wave*32 + (nt&1)*16 + lr];

    const f16x8* Wb = (const f16x8*)Wp + (size_t)((hb*4+wave)*8*ENC_KT)*64;
    f16x8 wreg[8][5];
    #pragma unroll
    for (int nt=0;nt<8;++nt){
        #pragma unroll
        for (int kt=0;kt<4;++kt) wreg[nt][kt] = Wb[(nt*ENC_KT + kt)*64 + lane];
        wreg[nt][4] = Wb[(nt*ENC_KT + 8)*64 + lane];
    }
    f16x8* wl = (f16x8*)wlds + (size_t)wave*(8*4*64);
    #pragma unroll
    for (int nt=0;nt<8;++nt)
        #pragma unroll
        for (int p=0;p<4;++p)
            wl[(nt*4 + p)*64 + lane] = Wb[(nt*ENC_KT + 4 + p)*64 + lane];

    __syncthreads();
    const int rr = tid/15, cc = tid - rr*15;
    const size_t xbase = (size_t)(row0+rr)*V_*EGO_ + cc;
    float xreg = 0.f;
    if (tid < 240){
        hcat[rr*HSTR + 128 + cc] = (f16)state[xbase];
        xreg = state[xbase + EGO_];
    }
    float c_reg[8], h_reg[8];
    #pragma unroll
    for (int i=0;i<8;++i){ c_reg[i]=0.f; h_reg[i]=0.f; }
    __syncthreads();
    const int Lmax = lmax_s;

    for (int t=0;t<Lmax;++t){
        uint32_t f0 = (uint32_t)t;
        if (t > 0 && lane < 4) f0 = ld_u32((const uint32_t*)&flags[pbid*4 + lane]);
        f32x4 acc[8];
        #pragma unroll
        for (int nt=0;nt<8;++nt) acc[nt] = (f32x4){bias_v[nt],bias_v[nt],bias_v[nt],bias_v[nt]};
        #pragma unroll
        for (int kt=0;kt<4;++kt){
            f16x8 a = *(const f16x8*)&hcat[lr*HSTR + kt*32 + quad*8];
            #pragma unroll
            for (int nt=0;nt<8;++nt) acc[nt] = MFMA(a, wreg[nt][kt], acc[nt]);
        }
        {
            f16x8 a = *(const f16x8*)&hcat[lr*HSTR + 128 + quad*8];
            #pragma unroll
            for (int nt=0;nt<8;++nt) acc[nt] = MFMA(a, wreg[nt][4], acc[nt]);
        }
        if (t > 0){
            f16x8 b0[8];
            #pragma unroll
            for (int nt=0;nt<8;++nt) b0[nt] = wl[(nt*4 + 0)*64 + lane];
            if (lane < 4){
                while (f0 < (uint32_t)t){
                    __builtin_amdgcn_s_sleep(1);
                    f0 = ld_u32((const uint32_t*)&flags[pbid*4 + lane]);
                }
            }
            const f16* src = ebuf + ((size_t)((t-1)&1)*256 + pbid)*2048 + lr*128 + quad*8;
            f16x8 a0,a1,a2,a3;
            bypass_ld4(a0,a1,a2,a3, src, src+32, src+64, src+96);
            #pragma unroll
            for (int nt=0;nt<8;++nt) acc[nt] = MFMA(a0, b0[nt], acc[nt]);
            #pragma unroll
            for (int nt=0;nt<8;++nt) acc[nt] = MFMA(a1, wl[(nt*4+1)*64+lane], acc[nt]);
            #pragma unroll
            for (int nt=0;nt<8;++nt) acc[nt] = MFMA(a2, wl[(nt*4+2)*64+lane], acc[nt]);
            #pragma unroll
            for (int nt=0;nt<8;++nt) acc[nt] = MFMA(a3, wl[(nt*4+3)*64+lane], acc[nt]);
        }
        __syncthreads();                     // B2
        #pragma unroll
        for (int s=0;s<2;++s){
            #pragma unroll
            for (int r=0;r<4;++r){
                int idx = s*4 + r;
                float gi = acc[s][r],   gf = acc[2+s][r];
                float gg = acc[4+s][r], go = acc[6+s][r];
                float cn = sigf(gf)*c_reg[idx] + sigf(gi)*tanh_fast(gg);
                float hn = sigf(go)*tanh_fast(cn);
                bool upd = (t < len_r[r]);
                c_reg[idx] = upd ? cn : c_reg[idx];
                h_reg[idx] = upd ? hn : h_reg[idx];
                hcat[(quad*4+r)*HSTR + wave*32 + s*16 + lr] = (f16)h_reg[idx];
            }
        }
        if (tid < 240) hcat[rr*HSTR + 128 + cc] = (f16)xreg;
        __syncthreads();                     // B3
        {
            f16x8 h8 = *(const f16x8*)&hcat[xr*HSTR + xc*8];
            f16* dst = ebuf + ((size_t)(t&1)*256 + bid)*2048 + xr*128 + xc*8;
            bypass_st(dst, h8);
        }
        vm_drain();
        if (lane == 0) st_u32((uint32_t*)&flags[bid*4 + wave], (uint32_t)(t+1));
        if (tid < 240){
            int tn = (t+2 < V_) ? (t+2) : (V_-1);
            xreg = state[xbase + (size_t)tn*EGO_];
        }
    }
    #pragma unroll
    for (int s=0;s<2;++s)
        #pragma unroll
        for (int r=0;r<4;++r)
            henc[(size_t)(row0+quad*4+r)*H_ + hb*128 + wave*32 + s*16 + lr] = (f16)h_reg[s*4+r];
}

// ---- generic GEMM: C = act(A[M,K] @ W[N,K]^T + bias) ----
template<bool RELU, bool F32OUT>
__global__ __launch_bounds__(256,2) void gemm_kernel(
    const f16* __restrict__ A, const f16* __restrict__ W,
    const float* __restrict__ bias, void* __restrict__ outp,
    int M, int N, int K)
{
    constexpr int ASTR = 40;
    __shared__ __align__(16) f16 As[64*ASTR];
    __shared__ __align__(16) f16 Ws[64*ASTR];
    const int tid = threadIdx.x;
    const int wave = tid>>6, lane = tid&63, lr = lane&15, quad = lane>>4;
    const int n0 = blockIdx.x*64, m0 = blockIdx.y*64;
    const int lrow = tid>>2, lk8 = (tid&3)*8;

    f32x4 acc[4];
    #pragma unroll
    for (int mt=0;mt<4;++mt) acc[mt] = (f32x4){0.f,0.f,0.f,0.f};

    for (int k0=0;k0<K;k0+=32){
        __syncthreads();
        *(f16x8*)&As[lrow*ASTR + lk8] = *(const f16x8*)&A[(size_t)(m0+lrow)*K + k0 + lk8];
        *(f16x8*)&Ws[lrow*ASTR + lk8] = *(const f16x8*)&W[(size_t)(n0+lrow)*K + k0 + lk8];
        __syncthreads();
        f16x8 b = *(const f16x8*)&Ws[(wave*16+lr)*ASTR + quad*8];
        #pragma unroll
        for (int mt=0;mt<4;++mt){
            f16x8 a = *(const f16x8*)&As[(mt*16+lr)*ASTR + quad*8];
            acc[mt] = MFMA(a, b, acc[mt]);
        }
    }
    float bv = bias[n0 + wave*16 + lr];
    #pragma unroll
    for (int mt=0;mt<4;++mt){
        #pragma unroll
        for (int r=0;r<4;++r){
            float v = acc[mt][r] + bv;
            if (RELU) v = fmaxf(v, 0.f);
            int m = m0 + mt*16 + quad*4 + r, n = n0 + wave*16 + lr;
            if (F32OUT) ((float*)outp)[(size_t)m*N + n] = v;
            else        ((f16*)outp)[(size_t)m*N + n] = (f16)v;
        }
    }
}

// ---- decoder: R2 pair-split + pi partials piggybacked in ebuf row ----------
__global__ __launch_bounds__(256,1) void decoder_kernel(
    const int* __restrict__ lengths, const f16* __restrict__ Wp,
    const float* __restrict__ xdec, const float* __restrict__ Wpi,
    const float* __restrict__ bpi, float* __restrict__ out,
    f16* __restrict__ ebufD, int* __restrict__ flags)
{
    __shared__ __align__(16) f16 wlds[4*8*4*64*8];   // 128 KB
    __shared__ __align__(16) f16 hbuf[MT*DSTR];
    __shared__ float part[4][16][2];
    __shared__ int lmax_s;
    const int tid = threadIdx.x;
    const int wave = tid>>6, lane = tid&63, lr = lane&15, quad = lane>>4;
    const int bid = blockIdx.x, hb = bid>>7, g = bid&127, pbid = bid^128;
    const int row0 = g*MT;
    const int xr = tid>>4, xc = tid&15;

    for (int i=tid;i<MT*DSTR;i+=256) hbuf[i] = (f16)0.f;
    if (tid < 64){
        int l = (lane<16) ? lengths[row0+lane] : 0;
        #pragma unroll
        for (int m=1;m<16;m<<=1){ int o = __shfl_xor(l, m, 64); l = (o>l)?o:l; }
        if (lane==0) lmax_s = l;
    }

    float xd[8][4];
    #pragma unroll
    for (int nt=0;nt<8;++nt){
        int n = (nt>>1)*256 + hb*128 + wave*32 + (nt&1)*16 + lr;
        #pragma unroll
        for (int r=0;r<4;++r) xd[nt][r] = xdec[(size_t)(row0+quad*4+r)*1024 + n];
    }
    float wpi_reg[2][2];
    #pragma unroll
    for (int a=0;a<2;++a)
        #pragma unroll
        for (int s=0;s<2;++s)
            wpi_reg[a][s] = Wpi[a*H_ + hb*128 + wave*32 + s*16 + lr];

    const f16x8* Wb = (const f16x8*)Wp + (size_t)((hb*4+wave)*8*DEC_KT)*64;
    f16x8 wreg[8][4];
    #pragma unroll
    for (int nt=0;nt<8;++nt)
        #pragma unroll
        for (int kt=0;kt<4;++kt)
            wreg[nt][kt] = Wb[(nt*DEC_KT + kt)*64 + lane];
    f16x8* wl = (f16x8*)wlds + (size_t)wave*(8*4*64);
    #pragma unroll
    for (int nt=0;nt<8;++nt)
        #pragma unroll
        for (int p=0;p<4;++p)
            wl[(nt*4 + p)*64 + lane] = Wb[(nt*DEC_KT + 4 + p)*64 + lane];

    float c_reg[8];
    #pragma unroll
    for (int i=0;i<8;++i) c_reg[i]=0.f;

    const int m_o = (tid>>1)&15, a_o = tid&1;
    const float bpi_o = bpi[a_o];
    const int len_o = (tid<32) ? lengths[row0+m_o] : 0;
    const size_t outbase = (size_t)(row0+m_o)*V_*2 + a_o;
    float own_prev = 0.f;

    __syncthreads();
    const int Lmax = lmax_s;

    for (int t=0;t<Lmax;++t){
        uint32_t f0 = (uint32_t)t;
        if (t > 0 && lane < 4) f0 = ld_u32((const uint32_t*)&flags[pbid*4 + lane]);
        f32x4 acc[8];
        #pragma unroll
        for (int nt=0;nt<8;++nt) acc[nt] = (f32x4){xd[nt][0],xd[nt][1],xd[nt][2],xd[nt][3]};
        #pragma unroll
        for (int kt=0;kt<4;++kt){
            f16x8 a = *(const f16x8*)&hbuf[lr*DSTR + kt*32 + quad*8];
            #pragma unroll
            for (int nt=0;nt<8;++nt) acc[nt] = MFMA(a, wreg[nt][kt], acc[nt]);
        }
        if (t > 0){
            f16x8 b0[8];
            #pragma unroll
            for (int nt=0;nt<8;++nt) b0[nt] = wl[(nt*4 + 0)*64 + lane];
            if (lane < 4){
                while (f0 < (uint32_t)t){
                    __builtin_amdgcn_s_sleep(1);
                    f0 = ld_u32((const uint32_t*)&flags[pbid*4 + lane]);
                }
            }
            const f16* srow = ebufD + ((size_t)((t-1)&1)*256 + pbid)*EBSTR;
            const f16* src = srow + lr*128 + quad*8;
            f16x8 a0,a1,a2,a3;
            uint32_t pv = 0;
            if (wave == 0){
                const uint32_t* pp = (const uint32_t*)srow + 1024 + (lane&31);
                bypass_ld4p(a0,a1,a2,a3, pv, src, src+32, src+64, src+96, pp);
            } else {
                bypass_ld4(a0,a1,a2,a3, src, src+32, src+64, src+96);
            }
            #pragma unroll
            for (int nt=0;nt<8;++nt) acc[nt] = MFMA(a0, b0[nt], acc[nt]);
            #pragma unroll
            for (int nt=0;nt<8;++nt) acc[nt] = MFMA(a1, wl[(nt*4+1)*64+lane], acc[nt]);
            #pragma unroll
            for (int nt=0;nt<8;++nt) acc[nt] = MFMA(a2, wl[(nt*4+2)*64+lane], acc[nt]);
            #pragma unroll
            for (int nt=0;nt<8;++nt) acc[nt] = MFMA(a3, wl[(nt*4+3)*64+lane], acc[nt]);
            // delayed pi output for step t-1: partner partials rode the same
            // ebuf row / flag / vmcnt window as the h-payload (piggyback).
            if (hb == 0 && tid < 32){
                float v = own_prev + __uint_as_float(pv) + bpi_o;
                v = tanh_fast(v);
                out[outbase + (size_t)(t-1)*2] = ((t-1) < len_o) ? v : 0.f;
            }
        }
        __syncthreads();                     // B2
        float spi[4][2];
        #pragma unroll
        for (int r=0;r<4;++r){ spi[r][0]=0.f; spi[r][1]=0.f; }
        #pragma unroll
        for (int s=0;s<2;++s){
            #pragma unroll
            for (int r=0;r<4;++r){
                int idx = s*4 + r;
                float gi = acc[s][r],   gf = acc[2+s][r];
                float gg = acc[4+s][r], go = acc[6+s][r];
                float cn = sigf(gf)*c_reg[idx] + sigf(gi)*tanh_fast(gg);
                c_reg[idx] = cn;
                float hn = sigf(go)*tanh_fast(cn);
                hbuf[(quad*4+r)*DSTR + wave*32 + s*16 + lr] = (f16)hn;
                spi[r][0] += cn*wpi_reg[0][s];
                spi[r][1] += cn*wpi_reg[1][s];
            }
        }
        #pragma unroll
        for (int msk=1; msk<16; msk<<=1){
            #pragma unroll
            for (int r=0;r<4;++r){
                spi[r][0] += __shfl_xor(spi[r][0], msk, 64);
                spi[r][1] += __shfl_xor(spi[r][1], msk, 64);
            }
        }
        if (lr == 0){
            #pragma unroll
            for (int r=0;r<4;++r){
                part[wave][quad*4+r][0] = spi[r][0];
                part[wave][quad*4+r][1] = spi[r][1];
            }
        }
        __syncthreads();                     // B3: h_t + part visible
        f16* drow = ebufD + ((size_t)(t&1)*256 + bid)*EBSTR;
        {
            f16x8 h8 = *(const f16x8*)&hbuf[xr*DSTR + xc*8];
            bypass_st(drow + xr*128 + xc*8, h8);
        }
        if (tid < 32){
            float own4 = part[0][m_o][a_o]+part[1][m_o][a_o]+part[2][m_o][a_o]+part[3][m_o][a_o];
            if (hb == 1) st_u32((uint32_t*)drow + 1024 + tid, __float_as_uint(own4));
            else         own_prev = own4;
        }
        vm_drain();                          // covers h + pi stores (wave 0)
        if (lane == 0) st_u32((uint32_t*)&flags[bid*4 + wave], (uint32_t)(t+1));
    }
    // epilogue: final pi output (step Lmax-1) + zero-fill t >= Lmax
    if (hb == 0 && tid < 32){
        uint32_t fv = ld_u32((const uint32_t*)&flags[pbid*4 + 0]);
        while (fv < (uint32_t)Lmax){
            __builtin_amdgcn_s_sleep(1);
            fv = ld_u32((const uint32_t*)&flags[pbid*4 + 0]);
        }
        const f16* srow = ebufD + ((size_t)((Lmax-1)&1)*256 + pbid)*EBSTR;
        uint32_t pu = ld_u32((const uint32_t*)srow + 1024 + tid);
        float v = own_prev + __uint_as_float(pu) + bpi_o;
        v = tanh_fast(v);
        out[outbase + (size_t)(Lmax-1)*2] = ((Lmax-1) < len_o) ? v : 0.f;
        for (int t=Lmax; t<V_; ++t) out[outbase + (size_t)t*2] = 0.f;
    }
}

extern "C" void kernel_launch(void* const* d_in, const int* in_sizes, int n_in,
                              void* d_out, int out_size, void* d_ws, size_t ws_size,
                              hipStream_t stream) {
    const float* state = (const float*)d_in[0];
    const int*   lengths=(const int*)d_in[1];
    const float* Wih1 = (const float*)d_in[2];
    const float* Whh1 = (const float*)d_in[3];
    const float* bih1 = (const float*)d_in[4];
    const float* bhh1 = (const float*)d_in[5];
    const float* W1   = (const float*)d_in[6];  const float* b1 = (const float*)d_in[7];
    const float* W2   = (const float*)d_in[8];  const float* b2 = (const float*)d_in[9];
    const float* W3   = (const float*)d_in[10]; const float* b3 = (const float*)d_in[11];
    const float* W4   = (const float*)d_in[12]; const float* b4 = (const float*)d_in[13];
    const float* Wih2 = (const float*)d_in[14]; const float* Whh2=(const float*)d_in[15];
    const float* bih2 = (const float*)d_in[16]; const float* bhh2=(const float*)d_in[17];
    const float* Wpi  = (const float*)d_in[18]; const float* bpi =(const float*)d_in[19];
    float* out = (float*)d_out;

    char* p = (char*)d_ws;
    auto alloc = [&](size_t bytes){ char* r = p; p += (bytes + 255) & ~(size_t)255; return r; };
    f16* WencP   = (f16*)alloc((size_t)2*4*8*ENC_KT*64*8*2);
    f16* WdecP   = (f16*)alloc((size_t)2*4*8*DEC_KT*64*8*2);
    f16* W1f     = (f16*)alloc((size_t)1024*256*2);
    f16* W2f     = (f16*)alloc((size_t)1024*1024*2);
    f16* W3f     = (f16*)alloc((size_t)512*1024*2);
    f16* W4f     = (f16*)alloc((size_t)256*512*2);
    f16* Wih2f   = (f16*)alloc((size_t)1024*256*2);
    float* biasE = (float*)alloc(1024*4);
    float* biasD = (float*)alloc(1024*4);
    f16* henc    = (f16*)alloc((size_t)2048*256*2);
    f16* act1    = (f16*)alloc((size_t)2048*1024*2);
    f16* act2    = (f16*)alloc((size_t)2048*1024*2);
    f16* act3    = (f16*)alloc((size_t)2048*512*2);
    f16* x4      = (f16*)alloc((size_t)2048*256*2);
    float* xdec  = (float*)alloc((size_t)2048*1024*4);
    f16* ebuf    = (f16*)alloc((size_t)2*256*2048*2);   // encoder exchange
    f16* ebufD   = (f16*)alloc((size_t)2*256*EBSTR*2);  // decoder exchange (+pi)
    int* flags   = (int*)alloc((size_t)2048*4);   // [0:1024)=enc, [1024:2048)=dec

    hipMemsetAsync(flags, 0, 2048*4, stream);

    prepack_enc<<<(2*4*8*ENC_KT*64+255)/256,256,0,stream>>>(Whh1, Wih1, WencP);
    prepack_dec<<<(2*4*8*DEC_KT*64+255)/256,256,0,stream>>>(Whh2, WdecP);
    bias_kernel<<<4,256,0,stream>>>(bih1,bhh1,bih2,bhh2,biasE,biasD);
    convert_kernel<<<(1024*256+255)/256,256,0,stream>>>(W1, W1f, 1024*256);
    convert_kernel<<<(1024*1024+255)/256,256,0,stream>>>(W2, W2f, 1024*1024);
    convert_kernel<<<(512*1024+255)/256,256,0,stream>>>(W3, W3f, 512*1024);
    convert_kernel<<<(256*512+255)/256,256,0,stream>>>(W4, W4f, 256*512);
    convert_kernel<<<(1024*256+255)/256,256,0,stream>>>(Wih2, Wih2f, 1024*256);

    encoder_kernel<<<256,256,0,stream>>>(state, lengths, WencP, biasE, henc, ebuf, flags);

    gemm_kernel<true ,false><<<dim3(16,32),256,0,stream>>>(henc, W1f, b1, act1, 2048,1024,256);
    gemm_kernel<true ,false><<<dim3(16,32),256,0,stream>>>(act1, W2f, b2, act2, 2048,1024,1024);
    gemm_kernel<true ,false><<<dim3( 8,32),256,0,stream>>>(act2, W3f, b3, act3, 2048, 512,1024);
    gemm_kernel<true ,false><<<dim3( 4,32),256,0,stream>>>(act3, W4f, b4, x4,   2048, 256, 512);
    gemm_kernel<false,true ><<<dim3(16,32),256,0,stream>>>(x4, Wih2f, biasD, xdec, 2048,1024,256);

    decoder_kernel<<<256,256,0,stream>>>(lengths, WdecP, xdec, Wpi, bpi, out,
                                         ebufD, flags+1024);
}